// Round 10
// baseline (152.958 us; speedup 1.0000x reference)
//
#include <hip/hip_runtime.h>

#define B_    4
#define CIN   64
#define COUT  64
#define KN    16
#define NPTS  32768
#define NPB   32      // points per block (fused kernel)

typedef __fp16 f16;
typedef __attribute__((ext_vector_type(8))) __fp16 half8;
typedef __attribute__((ext_vector_type(2))) __fp16 half2v;
typedef __attribute__((ext_vector_type(4))) float  f32x4;

static __device__ __forceinline__ half2v uint_as_h2(unsigned u) {
  union { unsigned u; half2v h; } c; c.u = u; return c.h;
}
static __device__ __forceinline__ unsigned h2_as_uint(half2v h) {
  union { unsigned u; half2v h; } c; c.h = h; return c.u;
}

static __device__ __forceinline__ float dot2_acc(half2v a, half2v b, float acc) {
#if __has_builtin(__builtin_amdgcn_fdot2)
  return __builtin_amdgcn_fdot2(a, b, acc, false);
#else
  return acc + (float)a.x * (float)b.x + (float)a.y * (float)b.y;
#endif
}

// ---------------------------------------------------------------------------
// K1 (all prep, ONE launch). Per block = 64 points of one batch:
//  1) transpose f f32[64][N] tile -> ft f16 [N][64] (gather row = 128B)
//  2) build rec[n] (32 dwords = 128B):
//       dw[0..7]   : idx packed 2x ushort
//       dw[8..15]  : dpx as 8x half2 (k-pairs)   dp = pos[idx] - pos[n]
//       dw[16..23] : dpy                          (f16, RTZ)
//       dw[24..31] : dpz
//     staged in LDS, dumped fully-coalesced (full 64B lines, no write amp)
//  3) blocks (y==0, x<64): Wt [64 o][256 c'] f16, c' = c*4 + d (d=3 -> wb)
// ---------------------------------------------------------------------------
__global__ __launch_bounds__(256) void prep_all_kernel(
    const float* __restrict__ f,       // [B][64][N]
    const float* __restrict__ pos,     // [B][3][N]
    const int*   __restrict__ nb,      // [B][16][N]
    const float* __restrict__ wtheta,  // [3][64][64]
    const float* __restrict__ wbias,   // [64][64]
    f16*         __restrict__ ft,      // [B][N][64]
    unsigned*    __restrict__ recG,    // [B][N][32 dw]
    f16*         __restrict__ Wt)      // [64][256]
{
  __shared__ union {
    float    tile[64][65];             // 16.6 KB
    unsigned recs[64][33];             // 8.4 KB (+1 pad: 2-way max = free)
  } sm;

  const int b    = blockIdx.y;
  const int n0   = blockIdx.x * 64;
  const int lane = threadIdx.x & 63;
  const int g    = threadIdx.x >> 6;

  // ---- 1) feature transpose + f16 cast ----
  const float* src = f + (size_t)b * CIN * NPTS + n0;
#pragma unroll
  for (int cc = 0; cc < 16; ++cc)
    sm.tile[cc * 4 + g][lane] = src[(size_t)(cc * 4 + g) * NPTS + lane];
  __syncthreads();
  f16* dst = ft + ((size_t)b * NPTS + n0) * CIN;
  const int nrow = threadIdx.x >> 5;
  const int c2   = (threadIdx.x & 31) * 2;
#pragma unroll
  for (int pass = 0; pass < 8; ++pass) {
    const int n = pass * 8 + nrow;
    half2v v = __builtin_amdgcn_cvt_pkrtz(sm.tile[c2][n], sm.tile[c2 + 1][n]);
    *(half2v*)&dst[(size_t)n * CIN + c2] = v;
  }
  __syncthreads();                      // tile dead; recs may overwrite

  // ---- 2) rec build: thread = (point p, k-quad kh) ----
  {
    const int p  = threadIdx.x & 63;
    const int kh = threadIdx.x >> 6;    // 0..3 -> k in [4kh, 4kh+4)
    const int n  = n0 + p;
    const float* pb = pos + (size_t)b * 3 * NPTS;
    const float cx = pb[n], cy = pb[NPTS + n], cz = pb[2 * NPTS + n];
    const int* nbb = nb + (size_t)b * KN * NPTS + n;
    int idx[4]; float dx[4], dy[4], dz[4];
#pragma unroll
    for (int j = 0; j < 4; ++j) {
      const int k = kh * 4 + j;
      idx[j] = nbb[(size_t)k * NPTS];                 // coalesced
      dx[j] = pb[idx[j]] - cx;                        // random 4B, L2-resident
      dy[j] = pb[NPTS + idx[j]] - cy;
      dz[j] = pb[2 * NPTS + idx[j]] - cz;
    }
#pragma unroll
    for (int jj = 0; jj < 2; ++jj) {
      const int dw = kh * 2 + jj;
      sm.recs[p][dw] = (unsigned)idx[2 * jj] | ((unsigned)idx[2 * jj + 1] << 16);
      sm.recs[p][8  + dw] = h2_as_uint(__builtin_amdgcn_cvt_pkrtz(dx[2 * jj], dx[2 * jj + 1]));
      sm.recs[p][16 + dw] = h2_as_uint(__builtin_amdgcn_cvt_pkrtz(dy[2 * jj], dy[2 * jj + 1]));
      sm.recs[p][24 + dw] = h2_as_uint(__builtin_amdgcn_cvt_pkrtz(dz[2 * jj], dz[2 * jj + 1]));
    }
  }

  // ---- 3) Wt pack ----
  if (b == 0 && blockIdx.x < 64) {
    const int t  = blockIdx.x * 256 + threadIdx.x;   // o*256 + c'
    const int o  = t >> 8;
    const int cp = t & 255;
    const int c  = cp >> 2;
    const int d  = cp & 3;
    const float v = (d < 3) ? wtheta[((size_t)d * 64 + c) * 64 + o]
                            : wbias[(size_t)c * 64 + o];
    Wt[t] = (f16)v;
  }
  __syncthreads();

  // ---- dump recs: thread t writes dwords [t*8, t*8+8) of the 2048-dw chunk
  {
    const int p = threadIdx.x >> 2;
    const int q = threadIdx.x & 3;
    unsigned* gdst = recG + ((size_t)b * NPTS + n0) * 32 + (size_t)threadIdx.x * 8;
#pragma unroll
    for (int j = 0; j < 8; ++j) gdst[j] = sm.recs[p][q * 8 + j];
  }
}

// ---------------------------------------------------------------------------
// K2 (fused): block = 32 points; wave wv owns 8 points.
// Phase B: per point, rec (uniform -> s_load): idx on SALU -> 16 coalesced
//   128B f16 gathers; contraction via v_dot2_f32_f16 with SGPR dp operand;
//   fsum via dot2 with (1,1).  Results -> LDS TL (f16, 544B row stride).
// Phase C: out[64x32] = Wt(64x256) . TL^T + bias via mfma_f32_16x16x32_f16.
// XCD swizzle: batch b -> XCDs {2b,2b+1} (feature table 4.2MB f16 L2-local).
// ---------------------------------------------------------------------------
__global__ __launch_bounds__(256) void flex_fused_kernel(
    const unsigned short* __restrict__ ftu,  // f16 bits [B][N][64]
    const unsigned* __restrict__ recG,       // [B][N][32 dw]
    const f16*      __restrict__ Wt,         // [64][256]
    const float*    __restrict__ bias,       // [64]
    float*          __restrict__ out)        // [B][64][N]
{
  __shared__ f16 TL[NPB][272];               // 17.4 KB (544B row stride)

  const int t    = threadIdx.x;
  const int lane = t & 63;
  const int wv   = __builtin_amdgcn_readfirstlane(t >> 6);

  const int xcd = blockIdx.x & 7;
  const int b   = xcd >> 1;
  const int loc = (xcd & 1) * ((NPTS / NPB) >> 1) + (blockIdx.x >> 3);
  const int n0  = loc * NPB;

  const char* fpk = (const char*)(ftu + (size_t)b * NPTS * CIN);
  const unsigned* recp = recG + ((size_t)b * NPTS + n0 + wv * 8) * 32;
  const half2v one2 = {(__fp16)1.0f, (__fp16)1.0f};

  // ---- phase B ----
#pragma unroll
  for (int p = 0; p < 8; ++p) {
    const unsigned* rp = recp + p * 32;      // uniform -> s_load
    unsigned iw[8];
#pragma unroll
    for (int j = 0; j < 8; ++j) iw[j] = rp[j];
    unsigned fvv[16];
#pragma unroll
    for (int k = 0; k < 16; ++k) {
      const unsigned off =
          (((k & 1) ? (iw[k >> 1] >> 16) : (iw[k >> 1] & 0xffffu)) << 7);
      fvv[k] = *(const unsigned short*)(fpk + off + lane * 2);  // 128B coalesced
    }
    float s0 = 0.f, s1 = 0.f, s2 = 0.f, fs = 0.f;
#pragma unroll
    for (int kk = 0; kk < 8; ++kk) {
      const half2v fp = uint_as_h2(fvv[2 * kk] | (fvv[2 * kk + 1] << 16));
      s0 = dot2_acc(uint_as_h2(rp[8  + kk]), fp, s0);
      s1 = dot2_acc(uint_as_h2(rp[16 + kk]), fp, s1);
      s2 = dot2_acc(uint_as_h2(rp[24 + kk]), fp, s2);
      fs = dot2_acc(one2, fp, fs);
    }
    uint2 pk;
    pk.x = h2_as_uint(__builtin_amdgcn_cvt_pkrtz(s0, s1));
    pk.y = h2_as_uint(__builtin_amdgcn_cvt_pkrtz(s2, fs));
    *(uint2*)&TL[wv * 8 + p][lane * 4] = pk;   // T[n][c*4+{0,1,2,3}]
  }
  __syncthreads();

  // ---- phase C ----
  {
    const int col  = lane & 15;
    const int krow = lane >> 4;                // 0..3
    const f16* wr = Wt + (size_t)(wv * 16 + col) * 256 + krow * 8;
    half8 a[8];
#pragma unroll
    for (int kk = 0; kk < 8; ++kk) a[kk] = *(const half8*)(wr + kk * 32);

    f32x4 acc[2];
    acc[0] = (f32x4){0.f, 0.f, 0.f, 0.f};
    acc[1] = (f32x4){0.f, 0.f, 0.f, 0.f};
#pragma unroll
    for (int nt = 0; nt < 2; ++nt) {
      const f16* tc = &TL[nt * 16 + col][0] + krow * 8;
#pragma unroll
      for (int kk = 0; kk < 8; ++kk) {
        half8 bf = *(const half8*)(tc + kk * 32);
        acc[nt] = __builtin_amdgcn_mfma_f32_16x16x32_f16(a[kk], bf, acc[nt], 0, 0, 0);
      }
    }

    const float4 bv = *(const float4*)(bias + wv * 16 + krow * 4);
    float* ob = out + ((size_t)b * COUT + wv * 16 + krow * 4) * NPTS + n0 + col;
#pragma unroll
    for (int r = 0; r < 4; ++r) {
      const float badd = (r == 0) ? bv.x : (r == 1) ? bv.y : (r == 2) ? bv.z : bv.w;
      float* orow = ob + (size_t)r * NPTS;
#pragma unroll
      for (int nt = 0; nt < 2; ++nt)
        __builtin_nontemporal_store(acc[nt][r] + badd, orow + nt * 16);
    }
  }
}

// ---------------------------------------------------------------------------
extern "C" void kernel_launch(void* const* d_in, const int* in_sizes, int n_in,
                              void* d_out, int out_size, void* d_ws, size_t ws_size,
                              hipStream_t stream) {
  const float* features = (const float*)d_in[0];   // [B][64][N]
  const float* wtheta   = (const float*)d_in[1];   // [3][64][64]
  const float* wbias    = (const float*)d_in[2];   // [64][64]
  const float* bias     = (const float*)d_in[3];   // [64]
  const int*   nb       = (const int*)  d_in[4];   // [B][16][N]
  const float* pos      = (const float*)d_in[5];   // [B][3][N]
  float* out = (float*)d_out;

  char* ws = (char*)d_ws;
  f16*      ft  = (f16*)ws;                               // 16.78 MB
  f16*      Wt  = (f16*)(ws + 16777216);                  // 32 KB
  unsigned* rec = (unsigned*)(ws + 16777216 + 32768);     // 16.78 MB (tot 33.6)

  prep_all_kernel<<<dim3(NPTS / 64, B_), 256, 0, stream>>>(
      features, pos, nb, wtheta, wbias, ft, rec, Wt);
  flex_fused_kernel<<<B_ * (NPTS / NPB), 256, 0, stream>>>(
      (const unsigned short*)ft, rec, Wt, bias, out);
}

// Round 11
// 141.416 us; speedup vs baseline: 1.0816x; 1.0816x over previous
//
#include <hip/hip_runtime.h>

#define B_    4
#define CIN   64
#define COUT  64
#define KN    16
#define NPTS  32768
#define NPB   32      // points per block (fused kernel)

typedef __fp16 f16;
typedef __attribute__((ext_vector_type(8))) __fp16 half8;
typedef __attribute__((ext_vector_type(2))) __fp16 half2v;
typedef __attribute__((ext_vector_type(4))) float  f32x4;

static __device__ __forceinline__ half2v uint_as_h2(unsigned u) {
  union { unsigned u; half2v h; } c; c.u = u; return c.h;
}
static __device__ __forceinline__ unsigned h2_as_uint(half2v h) {
  union { unsigned u; half2v h; } c; c.h = h; return c.u;
}
static __device__ __forceinline__ float dot2_acc(half2v a, half2v b, float acc) {
#if __has_builtin(__builtin_amdgcn_fdot2)
  return __builtin_amdgcn_fdot2(a, b, acc, false);
#else
  return acc + (float)a.x * (float)b.x + (float)a.y * (float)b.y;
#endif
}

// ---------------------------------------------------------------------------
// K0: positions [B][3][N] -> pt [B][N][4] float4  (1 cache line per gather)
// ---------------------------------------------------------------------------
__global__ __launch_bounds__(256) void pos_pack_kernel(
    const float* __restrict__ p, float4* __restrict__ pt) {
  const int b = blockIdx.y;
  const int n = blockIdx.x * 256 + threadIdx.x;
  const float* src = p + (size_t)b * 3 * NPTS;
  float4 v;
  v.x = src[n];
  v.y = src[NPTS + n];
  v.z = src[2 * NPTS + n];
  v.w = 0.f;
  pt[(size_t)b * NPTS + n] = v;
}

// ---------------------------------------------------------------------------
// K1: per block = 64 points of one batch:
//  1) transpose f f32[64][N] tile -> ft f16 [N][64] (gather row = 128B)
//  2) build rec[n] (32 dwords = 128B) using pt (ONE 16B line per neighbor):
//       dw[0..7]: idx 2x ushort | dw[8..15]: dpx half2 | [16..23]: dpy |
//       [24..31]: dpz      staged in LDS, dumped fully-coalesced
//  3) blocks (y==0, x<64): Wt [64 o][256 c'] f16, c' = c*4+d (d=3 -> wb)
// ---------------------------------------------------------------------------
__global__ __launch_bounds__(256) void prep_all_kernel(
    const float*  __restrict__ f,       // [B][64][N]
    const float4* __restrict__ pt,      // [B][N]
    const int*    __restrict__ nb,      // [B][16][N]
    const float*  __restrict__ wtheta,  // [3][64][64]
    const float*  __restrict__ wbias,   // [64][64]
    f16*          __restrict__ ft,      // [B][N][64]
    unsigned*     __restrict__ recG,    // [B][N][32 dw]
    f16*          __restrict__ Wt)      // [64][256]
{
  __shared__ union {
    float    tile[64][65];             // 16.6 KB
    unsigned recs[64][33];             // 8.4 KB
  } sm;

  const int b    = blockIdx.y;
  const int n0   = blockIdx.x * 64;
  const int lane = threadIdx.x & 63;
  const int g    = threadIdx.x >> 6;

  // ---- 1) feature transpose + f16 cast ----
  const float* src = f + (size_t)b * CIN * NPTS + n0;
#pragma unroll
  for (int cc = 0; cc < 16; ++cc)
    sm.tile[cc * 4 + g][lane] = src[(size_t)(cc * 4 + g) * NPTS + lane];
  __syncthreads();
  f16* dst = ft + ((size_t)b * NPTS + n0) * CIN;
  const int nrow = threadIdx.x >> 5;
  const int c2   = (threadIdx.x & 31) * 2;
#pragma unroll
  for (int pass = 0; pass < 8; ++pass) {
    const int n = pass * 8 + nrow;
    half2v v = __builtin_amdgcn_cvt_pkrtz(sm.tile[c2][n], sm.tile[c2 + 1][n]);
    *(half2v*)&dst[(size_t)n * CIN + c2] = v;
  }
  __syncthreads();                      // tile dead; recs may overwrite

  // ---- 2) rec build: thread = (point p, k-quad kh); 1 line per neighbor --
  {
    const int p  = threadIdx.x & 63;
    const int kh = threadIdx.x >> 6;    // 0..3 -> k in [4kh, 4kh+4)
    const int n  = n0 + p;
    const float4* ptb = pt + (size_t)b * NPTS;
    const float4  ctr = ptb[n];
    const int* nbb = nb + (size_t)b * KN * NPTS + n;
    int idx[4]; float dx[4], dy[4], dz[4];
#pragma unroll
    for (int j = 0; j < 4; ++j) {
      const int k = kh * 4 + j;
      idx[j] = nbb[(size_t)k * NPTS];                 // coalesced
      const float4 q = ptb[idx[j]];                   // random 16B, 1 line
      dx[j] = q.x - ctr.x;
      dy[j] = q.y - ctr.y;
      dz[j] = q.z - ctr.z;
    }
#pragma unroll
    for (int jj = 0; jj < 2; ++jj) {
      const int dw = kh * 2 + jj;
      sm.recs[p][dw] = (unsigned)idx[2 * jj] | ((unsigned)idx[2 * jj + 1] << 16);
      sm.recs[p][8  + dw] = h2_as_uint(__builtin_amdgcn_cvt_pkrtz(dx[2 * jj], dx[2 * jj + 1]));
      sm.recs[p][16 + dw] = h2_as_uint(__builtin_amdgcn_cvt_pkrtz(dy[2 * jj], dy[2 * jj + 1]));
      sm.recs[p][24 + dw] = h2_as_uint(__builtin_amdgcn_cvt_pkrtz(dz[2 * jj], dz[2 * jj + 1]));
    }
  }

  // ---- 3) Wt pack ----
  if (b == 0 && blockIdx.x < 64) {
    const int t  = blockIdx.x * 256 + threadIdx.x;   // o*256 + c'
    const int o  = t >> 8;
    const int cp = t & 255;
    const int c  = cp >> 2;
    const int d  = cp & 3;
    const float v = (d < 3) ? wtheta[((size_t)d * 64 + c) * 64 + o]
                            : wbias[(size_t)c * 64 + o];
    Wt[t] = (f16)v;
  }
  __syncthreads();

  // ---- dump recs fully coalesced ----
  {
    const int p = threadIdx.x >> 2;
    const int q = threadIdx.x & 3;
    unsigned* gdst = recG + ((size_t)b * NPTS + n0) * 32 + (size_t)threadIdx.x * 8;
#pragma unroll
    for (int j = 0; j < 8; ++j) gdst[j] = sm.recs[p][q * 8 + j];
  }
}

// ---------------------------------------------------------------------------
// K2 (fused): block = 32 points; wave wv owns 8 points, processed with
// unroll-2 (2 gather chains in flight -> ~32 live fvv VGPRs, no spill).
// Phase B: rec via uniform s_load; idx/addr on SALU; 16 coalesced 128B f16
//   gathers/point; contraction = v_dot2_f32_f16 (dp from SGPR).
// Phase C: out[64x32] = Wt(64x256) . TL^T + bias via mfma_f32_16x16x32_f16.
// XCD swizzle: batch b -> XCDs {2b,2b+1}.
// ---------------------------------------------------------------------------
__global__ __launch_bounds__(256, 4) void flex_fused_kernel(
    const unsigned short* __restrict__ ftu,  // f16 bits [B][N][64]
    const unsigned* __restrict__ recG,       // [B][N][32 dw]
    const f16*      __restrict__ Wt,         // [64][256]
    const float*    __restrict__ bias,       // [64]
    float*          __restrict__ out)        // [B][64][N]
{
  __shared__ f16 TL[NPB][272];               // 17.4 KB (544B row stride)

  const int t    = threadIdx.x;
  const int lane = t & 63;
  const int wv   = __builtin_amdgcn_readfirstlane(t >> 6);

  const int xcd = blockIdx.x & 7;
  const int b   = xcd >> 1;
  const int loc = (xcd & 1) * ((NPTS / NPB) >> 1) + (blockIdx.x >> 3);
  const int n0  = loc * NPB;

  const char* fpk = (const char*)(ftu + (size_t)b * NPTS * CIN);
  const unsigned* recp = recG + ((size_t)b * NPTS + n0 + wv * 8) * 32;
  const half2v one2 = {(__fp16)1.0f, (__fp16)1.0f};

  // ---- phase B ----
#pragma unroll 2
  for (int p = 0; p < 8; ++p) {
    const unsigned* rp = recp + p * 32;      // uniform -> s_load
    unsigned iw[8];
#pragma unroll
    for (int j = 0; j < 8; ++j) iw[j] = rp[j];
    unsigned fvv[16];
#pragma unroll
    for (int k = 0; k < 16; ++k) {
      const unsigned off =
          (((k & 1) ? (iw[k >> 1] >> 16) : (iw[k >> 1] & 0xffffu)) << 7);
      fvv[k] = *(const unsigned short*)(fpk + off + lane * 2);  // 128B coalesced
    }
    float s0 = 0.f, s1 = 0.f, s2 = 0.f, fs = 0.f;
#pragma unroll
    for (int kk = 0; kk < 8; ++kk) {
      const half2v fp = uint_as_h2(fvv[2 * kk] | (fvv[2 * kk + 1] << 16));
      s0 = dot2_acc(uint_as_h2(rp[8  + kk]), fp, s0);
      s1 = dot2_acc(uint_as_h2(rp[16 + kk]), fp, s1);
      s2 = dot2_acc(uint_as_h2(rp[24 + kk]), fp, s2);
      fs = dot2_acc(one2, fp, fs);
    }
    uint2 pk;
    pk.x = h2_as_uint(__builtin_amdgcn_cvt_pkrtz(s0, s1));
    pk.y = h2_as_uint(__builtin_amdgcn_cvt_pkrtz(s2, fs));
    *(uint2*)&TL[wv * 8 + p][lane * 4] = pk;   // T[n][c*4+{0,1,2,3}]
  }
  __syncthreads();

  // ---- phase C ----
  {
    const int col  = lane & 15;
    const int krow = lane >> 4;                // 0..3
    const f16* wr = Wt + (size_t)(wv * 16 + col) * 256 + krow * 8;
    half8 a[8];
#pragma unroll
    for (int kk = 0; kk < 8; ++kk) a[kk] = *(const half8*)(wr + kk * 32);

    f32x4 acc[2];
    acc[0] = (f32x4){0.f, 0.f, 0.f, 0.f};
    acc[1] = (f32x4){0.f, 0.f, 0.f, 0.f};
#pragma unroll
    for (int nt = 0; nt < 2; ++nt) {
      const f16* tc = &TL[nt * 16 + col][0] + krow * 8;
#pragma unroll
      for (int kk = 0; kk < 8; ++kk) {
        half8 bf = *(const half8*)(tc + kk * 32);
        acc[nt] = __builtin_amdgcn_mfma_f32_16x16x32_f16(a[kk], bf, acc[nt], 0, 0, 0);
      }
    }

    const float4 bv = *(const float4*)(bias + wv * 16 + krow * 4);
    float* ob = out + ((size_t)b * COUT + wv * 16 + krow * 4) * NPTS + n0 + col;
#pragma unroll
    for (int r = 0; r < 4; ++r) {
      const float badd = (r == 0) ? bv.x : (r == 1) ? bv.y : (r == 2) ? bv.z : bv.w;
      float* orow = ob + (size_t)r * NPTS;
#pragma unroll
      for (int nt = 0; nt < 2; ++nt)
        __builtin_nontemporal_store(acc[nt][r] + badd, orow + nt * 16);
    }
  }
}

// ---------------------------------------------------------------------------
extern "C" void kernel_launch(void* const* d_in, const int* in_sizes, int n_in,
                              void* d_out, int out_size, void* d_ws, size_t ws_size,
                              hipStream_t stream) {
  const float* features = (const float*)d_in[0];   // [B][64][N]
  const float* wtheta   = (const float*)d_in[1];   // [3][64][64]
  const float* wbias    = (const float*)d_in[2];   // [64][64]
  const float* bias     = (const float*)d_in[3];   // [64]
  const int*   nb       = (const int*)  d_in[4];   // [B][16][N]
  const float* pos      = (const float*)d_in[5];   // [B][3][N]
  float* out = (float*)d_out;

  char* ws = (char*)d_ws;
  f16*      ft  = (f16*)ws;                               // 16.78 MB
  float4*   pt  = (float4*)(ws + 16777216);               //  2.10 MB
  f16*      Wt  = (f16*)(ws + 16777216 + 2097152);        // 32 KB
  unsigned* rec = (unsigned*)(ws + 16777216 + 2097152 + 32768);  // 16.78 MB

  pos_pack_kernel<<<dim3(NPTS / 256, B_), 256, 0, stream>>>(pos, pt);
  prep_all_kernel<<<dim3(NPTS / 64, B_), 256, 0, stream>>>(
      features, pt, nb, wtheta, wbias, ft, rec, Wt);
  flex_fused_kernel<<<B_ * (NPTS / NPB), 256, 0, stream>>>(
      (const unsigned short*)ft, rec, Wt, bias, out);
}